// Round 9
// baseline (6029.939 us; speedup 1.0000x reference)
//
#include <hip/hip_runtime.h>
#include <hip/hip_bf16.h>

// ResNetTTT. Round 9: R8's role-split (16 waves: A=MFMA side, B=update side)
// with the VGPR fix: __launch_bounds__(1024, 1) -> 128-VGPR cap (1 block/CU is
// forced by 162KB LDS anyway). R8's (1024,4) budgeted for 4 blocks/CU -> 64
// VGPR -> 10MB/dispatch scratch spill.

#define ERF_CF 0.70710678118654752f
#define PDF_CF 0.3989422804014327f
#define ETA 0.025f   // TTT_LR / MB

typedef __attribute__((ext_vector_type(8))) short bfrag;    // 8 bf16 (4 VGPR)
typedef __attribute__((ext_vector_type(4))) float f32x4;

union FB { bfrag v; unsigned short u[8]; unsigned d[4]; };

__device__ __forceinline__ float wsum(float v) {
#pragma unroll
  for (int o = 32; o > 0; o >>= 1) v += __shfl_xor(v, o, 64);
  return v;
}

__device__ __forceinline__ unsigned pack_split(float x) {
  unsigned u = __float_as_uint(x);
  unsigned hb = u & 0xFFFF0000u;
  float lf = x - __uint_as_float(hb);
  return hb | (__float_as_uint(lf) >> 16);
}
__device__ __forceinline__ float uns(unsigned short hs, unsigned short ls) {
  return __uint_as_float((unsigned)hs << 16) + __uint_as_float((unsigned)ls << 16);
}
__device__ __forceinline__ float fb_el(const FB& H, const FB& L, int e) {
  return __uint_as_float((unsigned)H.u[e] << 16) +
         __uint_as_float((unsigned)L.u[e] << 16);
}
__device__ __forceinline__ void split2(float f, unsigned short& hs, unsigned short& ls) {
  unsigned u = __float_as_uint(f);
  unsigned hb = u & 0xFFFF0000u;
  hs = (unsigned short)(u >> 16);
  ls = (unsigned short)(__float_as_uint(f - __uint_as_float(hb)) >> 16);
}
__device__ __forceinline__ f32x4 mm3(bfrag ah, bfrag al, bfrag bh, bfrag bl, f32x4 acc) {
  acc = __builtin_amdgcn_mfma_f32_16x16x32_bf16(ah, bh, acc, 0, 0, 0);
  acc = __builtin_amdgcn_mfma_f32_16x16x32_bf16(ah, bl, acc, 0, 0, 0);
  acc = __builtin_amdgcn_mfma_f32_16x16x32_bf16(al, bh, acc, 0, 0, 0);
  return acc;
}

// ---------------------------------------------------------------------------
__global__ void prep_w(const float* __restrict__ c1w, const float* __restrict__ cw,
                       float* __restrict__ wt1, float* __restrict__ wt) {
  int id = blockIdx.x * 256 + threadIdx.x;
  if (id < 16384) {
    int ci = id >> 8, co = id & 255;
    wt1[id] = c1w[co * 64 + ci];
  }
  int id2 = id - 16384;
  if (id2 >= 0 && id2 < 1572864) {
    int cv = id2 / 196608;
    int r = id2 - cv * 196608;
    int k = r >> 8, co = r & 255;
    int tt = k >> 8, ci = k & 255;
    wt[id2] = cw[((cv * 256 + co) * 256 + ci) * 3 + tt];
  }
}

__global__ void zero_halo(float* __restrict__ bufA, float* __restrict__ bufB) {
  int id = blockIdx.x * 256 + threadIdx.x;
  int c = id & 255;
  int row = (id >> 8) & 1;
  int b = (id >> 9) & 3;
  float* p = (id >> 11) ? bufB : bufA;
  p[(b * 1026 + row * 1025) * 256 + c] = 0.0f;
}

template <int BIAS, int RELU, int RES, int OST, int ACC>
__global__ __launch_bounds__(256) void gemm_k(
    const float* __restrict__ A, const float* __restrict__ Wt,
    const float* __restrict__ bias, const float* __restrict__ res,
    float* __restrict__ out, float* __restrict__ accp,
    int M, int N, int K, int lda, int haloA) {
  __shared__ float As[16][68];
  __shared__ float Bs[16][64];
  const int tid = threadIdx.x;
  const int bm = blockIdx.x * 64, bn = blockIdx.y * 64;
  const int tx = tid & 15, ty = tid >> 4;
  float acc[4][4] = {};

  for (int k0 = 0; k0 < K; k0 += 16) {
#pragma unroll
    for (int i = 0; i < 4; ++i) {
      int idx = tid + i * 256;
      int kk = idx & 15, mm = idx >> 4;
      int m = bm + mm;
      int rb = m * lda + (haloA ? ((m >> 10) << 9) : 0);
      As[kk][mm] = A[rb + k0 + kk];
    }
#pragma unroll
    for (int i = 0; i < 4; ++i) {
      int idx = tid + i * 256;
      int nn = idx & 63, kk = idx >> 6;
      Bs[kk][nn] = Wt[(k0 + kk) * N + bn + nn];
    }
    __syncthreads();
#pragma unroll
    for (int kk = 0; kk < 16; ++kk) {
      float4 av = *(const float4*)&As[kk][ty * 4];
      float4 bv = *(const float4*)&Bs[kk][tx * 4];
      float aa[4] = {av.x, av.y, av.z, av.w};
      float bb[4] = {bv.x, bv.y, bv.z, bv.w};
#pragma unroll
      for (int i = 0; i < 4; ++i)
#pragma unroll
        for (int j = 0; j < 4; ++j) acc[i][j] = fmaf(aa[i], bb[j], acc[i][j]);
    }
    __syncthreads();
  }

  const int n0 = bn + tx * 4;
#pragma unroll
  for (int i = 0; i < 4; ++i) {
    int m = bm + ty * 4 + i;
    int b_ = m >> 10, l = m & 1023;
    float v[4];
#pragma unroll
    for (int j = 0; j < 4; ++j) {
      float x = acc[i][j];
      if constexpr (BIAS) x += bias[n0 + j];
      if constexpr (RELU) x = fmaxf(x, 0.0f);
      if constexpr (RES) x += res[m * N + n0 + j];
      v[j] = x;
    }
    float4 vv = make_float4(v[0], v[1], v[2], v[3]);
    if constexpr (OST == 0) {
      *(float4*)&out[m * N + n0] = vv;
    } else if constexpr (OST == 1) {
      *(float4*)&out[(b_ * 1026 + l + 1) * 256 + n0] = vv;
    } else {
      int hq = n0 >> 6;
      int oidx = (((b_ * 4 + hq) * 1024 + l) << 6) + (n0 & 63);
      *(float4*)&out[oidx] = vv;
    }
    if constexpr (ACC == 1) {
      *(float4*)&accp[m * 256 + n0] = vv;
    } else if constexpr (ACC == 2) {
      float4 s = *(const float4*)&accp[m * 256 + n0];
      s.x += vv.x; s.y += vv.y; s.z += vv.z; s.w += vv.w;
      *(float4*)&accp[m * 256 + n0] = s;
    }
  }
}

__global__ __launch_bounds__(256) void ln_kernel(const float* __restrict__ in,
                                                 float* __restrict__ o,
                                                 const float* __restrict__ w,
                                                 const float* __restrict__ bb,
                                                 float eps) {
  int row = blockIdx.x * 4 + (threadIdx.x >> 6);
  int l = threadIdx.x & 63;
  float4 v = ((const float4*)(in + (long)row * 256))[l];
  float s = wsum(v.x + v.y + v.z + v.w);
  float mu = s * (1.0f / 256.0f);
  float dx = v.x - mu, dy = v.y - mu, dz = v.z - mu, dw = v.w - mu;
  float rstd = rsqrtf(wsum(dx * dx + dy * dy + dz * dz + dw * dw) * (1.0f / 256.0f) + eps);
  float4 wv = ((const float4*)w)[l];
  float4 bv = ((const float4*)bb)[l];
  float4 r;
  r.x = wv.x * dx * rstd + bv.x;
  r.y = wv.y * dy * rstd + bv.y;
  r.z = wv.z * dz * rstd + bv.z;
  r.w = wv.w * dw * rstd + bv.w;
  ((float4*)(o + (long)row * 256))[l] = r;
}

// ---------------------------------------------------------------------------
// TTT scan via MFMA, 1024 threads (16 waves, 4/SIMD) per (b,h) chain.
// Waves 0-7 (A): W1 frags, S1/S3/S6, gelus, W1-upd, LN phases.
// Waves 8-15 (B): staging, prefetch, S2/S7, W2 & W2T RMWs.
// ---------------------------------------------------------------------------
__global__ __launch_bounds__(1024, 1) void ttt_mfma(
    const float* __restrict__ XQ, const float* __restrict__ XK,
    const float* __restrict__ XV, const float* __restrict__ W1i,
    const float* __restrict__ B1i, const float* __restrict__ W2i,
    const float* __restrict__ B2i, const float* __restrict__ LNW,
    const float* __restrict__ LNB, float* __restrict__ outp) {
  extern __shared__ char smem[];
  unsigned short* W2Hp  = (unsigned short*)smem;   // [256][72]
  unsigned short* W2Lp  = W2Hp + 256 * 72;
  unsigned short* W2THp = W2Lp + 256 * 72;         // [64][264]
  unsigned short* W2TLp = W2THp + 64 * 264;
  unsigned short* X2Hp  = W2TLp + 64 * 264;        // [4][272]
  unsigned short* X2Lp  = X2Hp + 4 * 272;
  unsigned short* xkHp  = X2Lp + 4 * 272;          // [4][80]
  unsigned short* xkLp  = xkHp + 4 * 80;
  unsigned short* xqHp  = xkLp + 4 * 80;
  unsigned short* xqLp  = xqHp + 4 * 80;
  unsigned short* gZHp  = xqLp + 4 * 80;           // [4][80]
  unsigned short* gZLp  = gZHp + 4 * 80;
  float* X2F  = (float*)(gZLp + 4 * 80);           // [4][264] fp32 X2
  float* gZ1f = X2F + 4 * 264;                     // [4][256]
  float* Z2f  = gZ1f + 1024;                       // [4][64] gZ2 fp32
  float* redS = Z2f + 256;                         // [2][4][64]
  float* xvL  = redS + 512;                        // [4][64]
  float* b2L  = xvL + 256;                         // [64]
  float* lwL  = b2L + 64;
  float* lbL  = lwL + 64;

  const int bh = blockIdx.x, b = bh >> 2, h = bh & 3;
  const int t = threadIdx.x;            // 0..1023
  const bool isA = t < 512;
  const int lane = t & 63;
  const int a = lane & 15, g = lane >> 4;
  const bool rowv = (a < 4), g0 = (g == 0);
  // A-side (waves 0-7)
  const int wA = t >> 6;                // valid 0..7 when isA
  const int c0 = isA ? (32 * wA + a) : 0;
  const int c1 = isA ? (32 * wA + 16 + a) : 16;
  // B-side (waves 8-15)
  const int u = t - 512;                // valid 0..511 when !isA
  const int wB = (t >> 6) & 7;
  const int kh = wB & 1;
  const int jc = (wB >> 1) * 16 + a;

  FB zf; zf.d[0] = zf.d[1] = zf.d[2] = zf.d[3] = 0;

  // ---- init: W1 fragments + b1 regs (A only) ----
  FB w1h[2][2], w1l[2][2];
  float b1r0 = 0.f, b1r1 = 0.f;
  if (isA) {
#pragma unroll
    for (int i = 0; i < 2; ++i) {
      int cc = 32 * wA + i * 16 + a;
#pragma unroll
      for (int kc = 0; kc < 2; ++kc) {
#pragma unroll
        for (int e = 0; e < 8; ++e) {
          int k = kc * 32 + g * 8 + e;
          unsigned p = pack_split(W1i[(h * 64 + k) * 256 + cc]);
          w1h[i][kc].u[e] = (unsigned short)(p >> 16);
          w1l[i][kc].u[e] = (unsigned short)(p & 0xFFFFu);
        }
      }
    }
    b1r0 = B1i[h * 256 + c0];
    b1r1 = B1i[h * 256 + c1];
  } else {
#pragma unroll
    for (int i = 0; i < 2; ++i)
#pragma unroll
      for (int kc = 0; kc < 2; ++kc) { w1h[i][kc] = zf; w1l[i][kc] = zf; }
  }

  // W2 + W2T planes (all threads)
  for (int i = 0; i < 16; ++i) {
    int id = t + i * 1024;
    int k = id >> 6, j = id & 63;
    unsigned p = pack_split(W2i[(h * 256 + k) * 64 + j]);
    W2Hp[k * 72 + j] = (unsigned short)(p >> 16);
    W2Lp[k * 72 + j] = (unsigned short)(p & 0xFFFFu);
    int j2 = id >> 8, k2 = id & 255;
    unsigned q = pack_split(W2i[(h * 256 + k2) * 64 + j2]);
    W2THp[j2 * 264 + k2] = (unsigned short)(q >> 16);
    W2TLp[j2 * 264 + k2] = (unsigned short)(q & 0xFFFFu);
  }
  if (t < 64) { b2L[t] = B2i[h * 64 + t]; lwL[t] = LNW[h * 64 + t]; lbL[t] = LNB[h * 64 + t]; }

  const long chain = (long)bh * 65536;
  float rk = 0.f, rv = 0.f, rq = 0.f;
  if (!isA) {
    if (u < 256) { rk = XK[chain + u]; rv = XV[chain + u]; }
    else         { rq = XQ[chain + (u - 256)]; }
  }

  for (int n = 0; n < 256; ++n) {
    // ---- stage inputs (B) ----
    if (!isA) {
      if (u < 256) {
        int m = u >> 6, k = u & 63;
        unsigned short hs, ls;
        split2(rk, hs, ls); xkHp[m * 80 + k] = hs; xkLp[m * 80 + k] = ls;
        xvL[u] = rv;
      } else {
        int m = (u - 256) >> 6, k = (u - 256) & 63;
        unsigned short hs, ls;
        split2(rq, hs, ls); xqHp[m * 80 + k] = hs; xqLp[m * 80 + k] = ls;
      }
    }
    __syncthreads();  // B1

    float gpA[4] = {0.f, 0.f, 0.f, 0.f}, gpB[4] = {0.f, 0.f, 0.f, 0.f};
    FB wtH[4], wtL[4];

    // ---- S1 (A): Z1 = xk @ W1 + b1 ; in-reg gelu -> X2 planes + X2F ----
    // ---- (B): preload S2's W2T fragments ----
    if (isA) {
      f32x4 A0 = (f32x4){b1r0, b1r0, b1r0, b1r0};
      f32x4 A1 = (f32x4){b1r1, b1r1, b1r1, b1r1};
#pragma unroll
      for (int kc = 0; kc < 2; ++kc) {
        int base = kc * 32 + g * 8;
        FB ah = zf, al = zf;
        if (rowv) {
          ah.v = *(const bfrag*)&xkHp[a * 80 + base];
          al.v = *(const bfrag*)&xkLp[a * 80 + base];
        }
        A0 = mm3(ah.v, al.v, w1h[0][kc].v, w1l[0][kc].v, A0);
        A1 = mm3(ah.v, al.v, w1h[1][kc].v, w1l[1][kc].v, A1);
      }
      if (g0) {
#pragma unroll
        for (int q = 0; q < 4; ++q) {
          float z = A0[q];
          float er = erff(z * ERF_CF);
          float hh = 0.5f * (1.0f + er);
          float x2 = z * hh;
          gpA[q] = hh + z * __expf(-0.5f * z * z) * PDF_CF;
          unsigned short hs, ls;
          split2(x2, hs, ls);
          X2Hp[q * 272 + c0] = hs; X2Lp[q * 272 + c0] = ls;
          X2F[q * 264 + c0] = x2;
          z = A1[q];
          er = erff(z * ERF_CF);
          hh = 0.5f * (1.0f + er);
          x2 = z * hh;
          gpB[q] = hh + z * __expf(-0.5f * z * z) * PDF_CF;
          split2(x2, hs, ls);
          X2Hp[q * 272 + c1] = hs; X2Lp[q * 272 + c1] = ls;
          X2F[q * 264 + c1] = x2;
        }
      }
    } else {
#pragma unroll
      for (int k4 = 0; k4 < 4; ++k4) {
        int base = (kh * 4 + k4) * 32 + g * 8;
        wtH[k4].v = *(const bfrag*)&W2THp[jc * 264 + base];
        wtL[k4].v = *(const bfrag*)&W2TLp[jc * 264 + base];
      }
    }
    __syncthreads();  // B2

    // ---- S2 (B): Z2 partials (split-K over kh) ----
    if (!isA) {
      f32x4 acc = (f32x4){0.f, 0.f, 0.f, 0.f};
#pragma unroll
      for (int k4 = 0; k4 < 4; ++k4) {
        int base = (kh * 4 + k4) * 32 + g * 8;
        FB ah = zf, al = zf;
        if (rowv) {
          ah.v = *(const bfrag*)&X2Hp[a * 272 + base];
          al.v = *(const bfrag*)&X2Lp[a * 272 + base];
        }
        acc = mm3(ah.v, al.v, wtH[k4].v, wtL[k4].v, acc);
      }
      if (g0) {
#pragma unroll
        for (int q = 0; q < 4; ++q) redS[(kh * 4 + q) * 64 + jc] = acc[q];
      }
    }
    __syncthreads();  // B3

    // ---- LN-l2-bwd (A waves 0-3) + global prefetch (B) ----
    if (t < 256) {
      int m = t >> 6, j = lane;
      float z2 = b2L[j] + redS[m * 64 + j] + redS[256 + m * 64 + j];
      float mu = wsum(z2) * (1.0f / 64.0f);
      float dv = z2 - mu;
      float var = wsum(dv * dv) * (1.0f / 64.0f);
      float stdv = sqrtf(var + 1e-6f);
      float zh = dv / stdv;
      float lw = lwL[j], lb = lbL[j];
      float xkf = uns(xkHp[m * 80 + j], xkLp[m * 80 + j]);
      float tgt = xvL[m * 64 + j] - xkf;
      float gg = lw * (lw * zh + lb - tgt);
      float gs = wsum(gg) * (1.0f / 64.0f);
      float gzs = wsum(gg * zh) * (1.0f / 64.0f);
      float gz2 = (gg - gs - zh * gzs) / stdv;
      unsigned short hs, ls;
      split2(gz2, hs, ls);
      gZHp[m * 80 + j] = hs; gZLp[m * 80 + j] = ls;
      Z2f[m * 64 + j] = gz2;
    } else if (!isA && n + 1 < 256) {
      long nb = chain + (long)(n + 1) * 256;
      if (u < 256) { rk = XK[nb + u]; rv = XV[nb + u]; }
      else         { rq = XQ[nb + (u - 256)]; }
    }
    __syncthreads();  // B4

    // ---- S3 (A, old W2 rows)  ∥  W2T RMW (B) ----
    if (isA) {
      f32x4 A0 = (f32x4){0.f, 0.f, 0.f, 0.f};
      f32x4 A1 = (f32x4){0.f, 0.f, 0.f, 0.f};
#pragma unroll
      for (int kc = 0; kc < 2; ++kc) {
        int base = kc * 32 + g * 8;
        FB ah = zf, al = zf, b0h, b0l, b1h, b1l;
        if (rowv) {
          ah.v = *(const bfrag*)&gZHp[a * 80 + base];
          al.v = *(const bfrag*)&gZLp[a * 80 + base];
        }
        b0h.v = *(const bfrag*)&W2Hp[c0 * 72 + base];
        b0l.v = *(const bfrag*)&W2Lp[c0 * 72 + base];
        b1h.v = *(const bfrag*)&W2Hp[c1 * 72 + base];
        b1l.v = *(const bfrag*)&W2Lp[c1 * 72 + base];
        A0 = mm3(ah.v, al.v, b0h.v, b0l.v, A0);
        A1 = mm3(ah.v, al.v, b1h.v, b1l.v, A1);
      }
      if (g0) {
#pragma unroll
        for (int q = 0; q < 4; ++q) {
          gZ1f[q * 256 + c0] = A0[q] * gpA[q];
          gZ1f[q * 256 + c1] = A1[q] * gpB[q];
        }
      }
    } else {
      int jr = u & 63, kb = (u >> 6) * 32;
      float gz0 = Z2f[jr], gz1 = Z2f[64 + jr], gz2 = Z2f[128 + jr], gz3 = Z2f[192 + jr];
#pragma unroll
      for (int kk = 0; kk < 32; kk += 8) {
        int kb8 = kb + kk;
        float x0[8], x1[8], x2[8], x3[8];
        *(float4*)&x0[0] = *(const float4*)&X2F[kb8];        *(float4*)&x0[4] = *(const float4*)&X2F[kb8 + 4];
        *(float4*)&x1[0] = *(const float4*)&X2F[264 + kb8];  *(float4*)&x1[4] = *(const float4*)&X2F[264 + kb8 + 4];
        *(float4*)&x2[0] = *(const float4*)&X2F[528 + kb8];  *(float4*)&x2[4] = *(const float4*)&X2F[528 + kb8 + 4];
        *(float4*)&x3[0] = *(const float4*)&X2F[792 + kb8];  *(float4*)&x3[4] = *(const float4*)&X2F[792 + kb8 + 4];
        FB oh, ol, nh, nl;
        oh.v = *(const bfrag*)&W2THp[jr * 264 + kb8];
        ol.v = *(const bfrag*)&W2TLp[jr * 264 + kb8];
#pragma unroll
        for (int e = 0; e < 8; ++e) {
          float uu = fmaf(x3[e], gz3, fmaf(x2[e], gz2, fmaf(x1[e], gz1, x0[e] * gz0)));
          float f = fmaf(-ETA, uu, fb_el(oh, ol, e));
          unsigned short hs, ls;
          split2(f, hs, ls);
          nh.u[e] = hs; nl.u[e] = ls;
        }
        *(bfrag*)&W2THp[jr * 264 + kb8] = nh.v;
        *(bfrag*)&W2TLp[jr * 264 + kb8] = nl.v;
      }
    }
    __syncthreads();  // B5

    // ---- (A): W1/b1 reg update ; S6 ; geluB   ∥   (B): W2 RMW + b2 ----
    if (isA) {
      float gzA0 = gZ1f[c0], gzA1 = gZ1f[256 + c0], gzA2 = gZ1f[512 + c0], gzA3 = gZ1f[768 + c0];
      float gzB0 = gZ1f[c1], gzB1 = gZ1f[256 + c1], gzB2 = gZ1f[512 + c1], gzB3 = gZ1f[768 + c1];
      b1r0 = fmaf(-ETA, ((gzA0 + gzA1) + gzA2) + gzA3, b1r0);
      b1r1 = fmaf(-ETA, ((gzB0 + gzB1) + gzB2) + gzB3, b1r1);
#pragma unroll
      for (int kc = 0; kc < 2; ++kc) {
        int base = kc * 32 + g * 8;
        FB x0h, x0l, x1h, x1l, x2h, x2l, x3h, x3l;
        x0h.v = *(const bfrag*)&xkHp[base];       x0l.v = *(const bfrag*)&xkLp[base];
        x1h.v = *(const bfrag*)&xkHp[80 + base];  x1l.v = *(const bfrag*)&xkLp[80 + base];
        x2h.v = *(const bfrag*)&xkHp[160 + base]; x2l.v = *(const bfrag*)&xkLp[160 + base];
        x3h.v = *(const bfrag*)&xkHp[240 + base]; x3l.v = *(const bfrag*)&xkLp[240 + base];
#pragma unroll
        for (int e = 0; e < 8; ++e) {
          float k0 = fb_el(x0h, x0l, e), k1 = fb_el(x1h, x1l, e);
          float k2 = fb_el(x2h, x2l, e), k3 = fb_el(x3h, x3l, e);
          float uA = fmaf(k3, gzA3, fmaf(k2, gzA2, fmaf(k1, gzA1, k0 * gzA0)));
          float uB = fmaf(k3, gzB3, fmaf(k2, gzB2, fmaf(k1, gzB1, k0 * gzB0)));
          float fA = fmaf(-ETA, uA, fb_el(w1h[0][kc], w1l[0][kc], e));
          float fB = fmaf(-ETA, uB, fb_el(w1h[1][kc], w1l[1][kc], e));
          unsigned short hs, ls;
          split2(fA, hs, ls); w1h[0][kc].u[e] = hs; w1l[0][kc].u[e] = ls;
          split2(fB, hs, ls); w1h[1][kc].u[e] = hs; w1l[1][kc].u[e] = ls;
        }
      }
      // S6: Z1q = xq @ W1' + b1' ; in-reg gelu -> X2 planes
      {
        f32x4 A0 = (f32x4){b1r0, b1r0, b1r0, b1r0};
        f32x4 A1 = (f32x4){b1r1, b1r1, b1r1, b1r1};
#pragma unroll
        for (int kc = 0; kc < 2; ++kc) {
          int base = kc * 32 + g * 8;
          FB ah = zf, al = zf;
          if (rowv) {
            ah.v = *(const bfrag*)&xqHp[a * 80 + base];
            al.v = *(const bfrag*)&xqLp[a * 80 + base];
          }
          A0 = mm3(ah.v, al.v, w1h[0][kc].v, w1l[0][kc].v, A0);
          A1 = mm3(ah.v, al.v, w1h[1][kc].v, w1l[1][kc].v, A1);
        }
        if (g0) {
#pragma unroll
          for (int q = 0; q < 4; ++q) {
            float z = A0[q];
            float x2 = 0.5f * z * (1.0f + erff(z * ERF_CF));
            unsigned short hs, ls;
            split2(x2, hs, ls);
            X2Hp[q * 272 + c0] = hs; X2Lp[q * 272 + c0] = ls;
            z = A1[q];
            x2 = 0.5f * z * (1.0f + erff(z * ERF_CF));
            split2(x2, hs, ls);
            X2Hp[q * 272 + c1] = hs; X2Lp[q * 272 + c1] = ls;
          }
        }
      }
    } else {
      int kr = u & 255, jh = (u >> 8) * 32;
      float xk0 = X2F[kr], xk1 = X2F[264 + kr], xk2 = X2F[528 + kr], xk3 = X2F[792 + kr];
#pragma unroll
      for (int jj = 0; jj < 32; jj += 8) {
        int jb = jh + jj;
        float g0f[8], g1f[8], g2f[8], g3f[8];
        *(float4*)&g0f[0] = *(const float4*)&Z2f[jb];        *(float4*)&g0f[4] = *(const float4*)&Z2f[jb + 4];
        *(float4*)&g1f[0] = *(const float4*)&Z2f[64 + jb];   *(float4*)&g1f[4] = *(const float4*)&Z2f[64 + jb + 4];
        *(float4*)&g2f[0] = *(const float4*)&Z2f[128 + jb];  *(float4*)&g2f[4] = *(const float4*)&Z2f[128 + jb + 4];
        *(float4*)&g3f[0] = *(const float4*)&Z2f[192 + jb];  *(float4*)&g3f[4] = *(const float4*)&Z2f[192 + jb + 4];
        FB oh, ol, nh, nl;
        oh.v = *(const bfrag*)&W2Hp[kr * 72 + jb];
        ol.v = *(const bfrag*)&W2Lp[kr * 72 + jb];
#pragma unroll
        for (int e = 0; e < 8; ++e) {
          float uu = fmaf(xk3, g3f[e], fmaf(xk2, g2f[e], fmaf(xk1, g1f[e], xk0 * g0f[e])));
          float f = fmaf(-ETA, uu, fb_el(oh, ol, e));
          unsigned short hs, ls;
          split2(f, hs, ls);
          nh.u[e] = hs; nl.u[e] = ls;
        }
        *(bfrag*)&W2Hp[kr * 72 + jb] = nh.v;
        *(bfrag*)&W2Lp[kr * 72 + jb] = nl.v;
      }
      if (u < 64)
        b2L[u] -= ETA * (((Z2f[u] + Z2f[64 + u]) + Z2f[128 + u]) + Z2f[192 + u]);
    }
    __syncthreads();  // B6

    // ---- S7 (B): Z2q partials (updated W2T) ----
    if (!isA) {
      f32x4 acc = (f32x4){0.f, 0.f, 0.f, 0.f};
#pragma unroll
      for (int k4 = 0; k4 < 4; ++k4) {
        int base = (kh * 4 + k4) * 32 + g * 8;
        FB ah = zf, al = zf, bhf, blf;
        if (rowv) {
          ah.v = *(const bfrag*)&X2Hp[a * 272 + base];
          al.v = *(const bfrag*)&X2Lp[a * 272 + base];
        }
        bhf.v = *(const bfrag*)&W2THp[jc * 264 + base];
        blf.v = *(const bfrag*)&W2TLp[jc * 264 + base];
        acc = mm3(ah.v, al.v, bhf.v, blf.v, acc);
      }
      if (g0) {
#pragma unroll
        for (int q = 0; q < 4; ++q) redS[(kh * 4 + q) * 64 + jc] = acc[q];
      }
    }
    __syncthreads();  // B7

    // ---- LN fwd + residual + output (A waves 0-3) ----
    if (t < 256) {
      int m = t >> 6, j = lane;
      float z = b2L[j] + redS[m * 64 + j] + redS[256 + m * 64 + j];
      float mu = wsum(z) * (1.0f / 64.0f);
      float dv = z - mu;
      float var = wsum(dv * dv) * (1.0f / 64.0f);
      float rstd = rsqrtf(var + 1e-6f);
      float xqf = uns(xqHp[m * 80 + j], xqLp[m * 80 + j]);
      float val = lwL[j] * dv * rstd + lbL[j] + xqf;
      outp[((long)(b * 1024 + n * 4 + m)) * 256 + h * 64 + j] = val;
    }
    __syncthreads();  // B8
  }
}

// final (4096,64) @ (64,1) + b
__global__ __launch_bounds__(256) void fc3_kernel(const float* __restrict__ f2,
                                                  const float* __restrict__ w,
                                                  const float* __restrict__ bias,
                                                  float* __restrict__ o) {
  int m = blockIdx.x * 4 + (threadIdx.x >> 6);
  int lane = threadIdx.x & 63;
  float v = f2[m * 64 + lane] * w[lane];
  v = wsum(v);
  if (lane == 0) o[m] = v + bias[0];
}

// ---------------------------------------------------------------------------
extern "C" void kernel_launch(void* const* d_in, const int* in_sizes, int n_in,
                              void* d_out, int out_size, void* d_ws, size_t ws_size,
                              hipStream_t stream) {
  const float* x       = (const float*)d_in[0];
  const float* conv1_w = (const float*)d_in[1];
  const float* conv1_b = (const float*)d_in[2];
  const float* convs_w = (const float*)d_in[3];
  const float* convs_b = (const float*)d_in[4];
  const float* ln_w    = (const float*)d_in[5];
  const float* ln_b    = (const float*)d_in[6];
  const float* wq      = (const float*)d_in[7];
  const float* wk      = (const float*)d_in[8];
  const float* wv      = (const float*)d_in[9];
  const float* wo      = (const float*)d_in[10];
  const float* ttt_W1  = (const float*)d_in[11];
  const float* ttt_b1  = (const float*)d_in[12];
  const float* ttt_W2  = (const float*)d_in[13];
  const float* ttt_b2  = (const float*)d_in[14];
  const float* ttt_lnw = (const float*)d_in[15];
  const float* ttt_lnb = (const float*)d_in[16];
  const float* fc_w    = (const float*)d_in[17];
  const float* fc_b    = (const float*)d_in[18];
  const float* fc2_w   = (const float*)d_in[19];
  const float* fc2_b   = (const float*)d_in[20];
  const float* fc3_w   = (const float*)d_in[21];
  const float* fc3_b   = (const float*)d_in[22];

  float* ws = (float*)d_ws;
  float* wt1  = ws + 0;
  float* wt   = ws + 16384;
  float* bufA = ws + 1589248;
  float* bufB = ws + 2639872;
  float* sum4 = ws + 3690496;
  float* tln  = ws + 4739072;
  float* XQ   = ws + 5787648;
  float* XK   = ws + 6836224;
  float* XV   = ws + 7884800;
  float* tout = ws + 8933376;
  float* tfull = sum4;
  float* h2    = bufA;
  float* f1    = XQ;
  float* f2    = tout;

  const int M = 4096;
  dim3 blk(256);

  zero_halo<<<16, blk, 0, stream>>>(bufA, bufB);
  prep_w<<<6208, blk, 0, stream>>>(conv1_w, convs_w, wt1, wt);

  gemm_k<1, 1, 0, 1, 0><<<dim3(64, 4), blk, 0, stream>>>(
      x, wt1, conv1_b, nullptr, bufA, nullptr, M, 256, 64, 64, 0);

  for (int i = 0; i < 8; ++i) {
    const float* in = (i % 2 == 0) ? bufA : bufB;
    float* out = (i % 2 == 0) ? bufB : bufA;
    const float* wp = wt + (size_t)i * 196608;
    const float* bp = convs_b + i * 256;
    if (i == 1)
      gemm_k<1, 1, 0, 1, 1><<<dim3(64, 4), blk, 0, stream>>>(
          in, wp, bp, nullptr, out, sum4, M, 256, 768, 256, 1);
    else if (i == 3 || i == 5 || i == 7)
      gemm_k<1, 1, 0, 1, 2><<<dim3(64, 4), blk, 0, stream>>>(
          in, wp, bp, nullptr, out, sum4, M, 256, 768, 256, 1);
    else
      gemm_k<1, 1, 0, 1, 0><<<dim3(64, 4), blk, 0, stream>>>(
          in, wp, bp, nullptr, out, sum4, M, 256, 768, 256, 1);
  }

  ln_kernel<<<1024, blk, 0, stream>>>(sum4, tln, ln_w, ln_b, 1e-5f);

  gemm_k<0, 0, 0, 2, 0><<<dim3(64, 4), blk, 0, stream>>>(
      tln, wq, nullptr, nullptr, XQ, nullptr, M, 256, 256, 256, 0);
  gemm_k<0, 0, 0, 2, 0><<<dim3(64, 4), blk, 0, stream>>>(
      tln, wk, nullptr, nullptr, XK, nullptr, M, 256, 256, 256, 0);
  gemm_k<0, 0, 0, 2, 0><<<dim3(64, 4), blk, 0, stream>>>(
      tln, wv, nullptr, nullptr, XV, nullptr, M, 256, 256, 256, 0);

  // TTT scan (MFMA): 16 chains, 1024 threads, 162688 B dynamic LDS
  const int TTT_LDS = 162688;
  (void)hipFuncSetAttribute((const void*)ttt_mfma,
                            hipFuncAttributeMaxDynamicSharedMemorySize, TTT_LDS);
  ttt_mfma<<<16, dim3(1024), TTT_LDS, stream>>>(XQ, XK, XV, ttt_W1, ttt_b1,
                                                ttt_W2, ttt_b2, ttt_lnw, ttt_lnb,
                                                tout);

  gemm_k<0, 0, 1, 0, 0><<<dim3(64, 4), blk, 0, stream>>>(
      tout, wo, nullptr, tln, tfull, nullptr, M, 256, 256, 256, 0);

  ln_kernel<<<1024, blk, 0, stream>>>(tfull, h2, ln_w, ln_b, 1e-5f);

  gemm_k<1, 0, 0, 0, 0><<<dim3(64, 8), blk, 0, stream>>>(
      h2, fc_w, fc_b, nullptr, f1, nullptr, M, 512, 256, 256, 0);
  gemm_k<1, 0, 0, 0, 0><<<dim3(64, 1), blk, 0, stream>>>(
      f1, fc2_w, fc2_b, nullptr, f2, nullptr, M, 64, 512, 512, 0);
  fc3_kernel<<<1024, blk, 0, stream>>>(f2, fc3_w, fc3_b, (float*)d_out);
}

// Round 10
// 2930.896 us; speedup vs baseline: 2.0574x; 2.0574x over previous
//
#include <hip/hip_runtime.h>
#include <hip/hip_bf16.h>

// ResNetTTT. Round 10: TTT reverted to verified R7 (512thr, (512,2), 128 VGPR,
// 2.51ms). All conv/QKV/wo/FC GEMMs replaced by direct-from-global split-bf16
// MFMA GEMM (hi/lo planes, 3-MFMA mm3, no LDS/no barriers in K-loop).
// Activations travel between GEMMs as hi/lo ushort planes (split once in the
// epilogue). Workspace aliased to stay under the proven 39.9MB high-water.

#define ERF_CF 0.70710678118654752f
#define PDF_CF 0.3989422804014327f
#define ETA 0.025f   // TTT_LR / MB

typedef __attribute__((ext_vector_type(8))) short bfrag;    // 8 bf16 (4 VGPR)
typedef __attribute__((ext_vector_type(4))) float f32x4;

union FB { bfrag v; unsigned short u[8]; unsigned d[4]; };

__device__ __forceinline__ float wsum(float v) {
#pragma unroll
  for (int o = 32; o > 0; o >>= 1) v += __shfl_xor(v, o, 64);
  return v;
}

__device__ __forceinline__ unsigned pack_split(float x) {
  unsigned u = __float_as_uint(x);
  unsigned hb = u & 0xFFFF0000u;
  float lf = x - __uint_as_float(hb);
  return hb | (__float_as_uint(lf) >> 16);
}
__device__ __forceinline__ float uns(unsigned short hs, unsigned short ls) {
  return __uint_as_float((unsigned)hs << 16) + __uint_as_float((unsigned)ls << 16);
}
__device__ __forceinline__ float fb_el(const FB& H, const FB& L, int e) {
  return __uint_as_float((unsigned)H.u[e] << 16) +
         __uint_as_float((unsigned)L.u[e] << 16);
}
__device__ __forceinline__ void split2(float f, unsigned short& hs, unsigned short& ls) {
  unsigned u = __float_as_uint(f);
  unsigned hb = u & 0xFFFF0000u;
  hs = (unsigned short)(u >> 16);
  ls = (unsigned short)(__float_as_uint(f - __uint_as_float(hb)) >> 16);
}
__device__ __forceinline__ f32x4 mm3(bfrag ah, bfrag al, bfrag bh, bfrag bl, f32x4 acc) {
  acc = __builtin_amdgcn_mfma_f32_16x16x32_bf16(ah, bh, acc, 0, 0, 0);
  acc = __builtin_amdgcn_mfma_f32_16x16x32_bf16(ah, bl, acc, 0, 0, 0);
  acc = __builtin_amdgcn_mfma_f32_16x16x32_bf16(al, bh, acc, 0, 0, 0);
  return acc;
}

// ---------------------------------------------------------------------------
// prep_all: split all weights into hi/lo bf16 planes, layout [n][k].
// job ranges: [0,16384) wt1 | [.. +1572864) convs | [.. +262144) q/k/v/o |
//             [.. +131072) fc | [.. +32768) fc2.  total = 2,015,232.
// ---------------------------------------------------------------------------
__global__ __launch_bounds__(256) void prep_all(
    const float* __restrict__ c1w, const float* __restrict__ cw,
    const float* __restrict__ wq, const float* __restrict__ wk,
    const float* __restrict__ wv, const float* __restrict__ wo_,
    const float* __restrict__ fcw, const float* __restrict__ fc2w,
    unsigned short* __restrict__ WH, unsigned short* __restrict__ WL) {
  int id = blockIdx.x * 256 + threadIdx.x;
  float val;
  if (id < 16384) {
    val = c1w[id];                       // [co][ci] == [n][k] already
  } else if (id < 1589248) {
    int j = id - 16384;
    int cv = j / 196608;
    int r = j - cv * 196608;
    int co = r / 768;
    int k = r - co * 768;
    int tt = k >> 8, ci = k & 255;
    val = cw[((cv * 256 + co) * 256 + ci) * 3 + tt];
  } else if (id < 1851392) {
    int j = id - 1589248;
    int which = j >> 16;
    int r = j & 65535;
    int out = r >> 8, in = r & 255;
    const float* Wp = which == 0 ? wq : which == 1 ? wk : which == 2 ? wv : wo_;
    val = Wp[in * 256 + out];
  } else if (id < 1982464) {
    int j = id - 1851392;
    int out = j >> 8, in = j & 255;
    val = fcw[in * 512 + out];
  } else {
    int j = id - 1982464;
    int out = j >> 9, in = j & 511;
    val = fc2w[in * 64 + out];
  }
  unsigned short hs, ls;
  split2(val, hs, ls);
  WH[id] = hs;
  WL[id] = ls;
}

// zero halo rows of the conv activation planes (A and B buffers, hi+lo)
__global__ __launch_bounds__(256) void zero_halo_pl(
    unsigned short* __restrict__ cAH, unsigned short* __restrict__ cAL,
    unsigned short* __restrict__ cBH, unsigned short* __restrict__ cBL) {
  int id = blockIdx.x * 256 + threadIdx.x;  // 0..8191
  int buf = id >> 11;
  int r = id & 2047;
  int b = r >> 9, row = (r >> 8) & 1, c = r & 255;
  unsigned short* p = buf == 0 ? cAH : buf == 1 ? cAL : buf == 2 ? cBH : cBL;
  p[(b * 1026 + row * 1025) * 256 + c] = 0;
}

// ---------------------------------------------------------------------------
// Direct-from-global split-bf16 MFMA GEMM. BM=32, BN=64, 256 threads (4 waves).
// Wave w: strip s=w>>1 (rows bm+16s..+15), col-half ch=w&1 (2 col-tiles).
// AF32: A is fp32 (on-the-fly split). HALOA: conv halo addressing.
// EPI: 0 fp32 out[m*N+c]; 1 halo planes; 2 qkv fp32 scatter; 3 planes;
//      4 fp32 out + residual from planes.  ACC: 0/1 store/2 add into acc4.
// ---------------------------------------------------------------------------
template <int AF32, int HALOA, int BIAS, int RELU, int EPI, int ACC>
__global__ __launch_bounds__(256) void gemm_mf(
    const unsigned short* __restrict__ AH, const unsigned short* __restrict__ AL,
    const float* __restrict__ Af32,
    const unsigned short* __restrict__ BH, const unsigned short* __restrict__ BL,
    const float* __restrict__ bias,
    const unsigned short* __restrict__ resH, const unsigned short* __restrict__ resL,
    float* __restrict__ outF, unsigned short* __restrict__ outH,
    unsigned short* __restrict__ outL, float* __restrict__ acc4,
    int N, int K) {
  const int tid = threadIdx.x;
  const int w = tid >> 6, lane = tid & 63;
  const int a = lane & 15, g = lane >> 4;
  const int s = w >> 1, ch = w & 1;
  const int bm = blockIdx.x * 32, bn = blockIdx.y * 64;
  const int rowA = bm + 16 * s + a;
  long abase;
  if constexpr (HALOA)
    abase = (long)((rowA >> 10) * 1026 + (rowA & 1023)) * 256;
  else
    abase = (long)rowA * K;
  const int cb0 = bn + (ch * 2) * 16 + a;
  const int cb1 = cb0 + 16;
  f32x4 acc0 = {0.f, 0.f, 0.f, 0.f}, acc1 = {0.f, 0.f, 0.f, 0.f};
#pragma unroll 2
  for (int kk = 0; kk < K; kk += 32) {
    FB ah, al;
    if constexpr (AF32) {
      const float* ap = Af32 + abase + kk + g * 8;
      float av[8];
      *(float4*)&av[0] = *(const float4*)ap;
      *(float4*)&av[4] = *(const float4*)(ap + 4);
#pragma unroll
      for (int e = 0; e < 8; ++e) split2(av[e], ah.u[e], al.u[e]);
    } else {
      ah.v = *(const bfrag*)&AH[abase + kk + g * 8];
      al.v = *(const bfrag*)&AL[abase + kk + g * 8];
    }
    FB b0h, b0l, b1h, b1l;
    b0h.v = *(const bfrag*)&BH[(long)cb0 * K + kk + g * 8];
    b0l.v = *(const bfrag*)&BL[(long)cb0 * K + kk + g * 8];
    b1h.v = *(const bfrag*)&BH[(long)cb1 * K + kk + g * 8];
    b1l.v = *(const bfrag*)&BL[(long)cb1 * K + kk + g * 8];
    acc0 = mm3(ah.v, al.v, b0h.v, b0l.v, acc0);
    acc1 = mm3(ah.v, al.v, b1h.v, b1l.v, acc1);
  }
#pragma unroll
  for (int i = 0; i < 2; ++i) {
    f32x4 av = i ? acc1 : acc0;
    int col = i ? cb1 : cb0;
    float bv = 0.f;
    if constexpr (BIAS) bv = bias[col];
#pragma unroll
    for (int q = 0; q < 4; ++q) {
      int r = bm + 16 * s + g * 4 + q;
      float val = av[q] + bv;
      if constexpr (RELU) val = fmaxf(val, 0.f);
      if constexpr (EPI == 4) {
        long ri = (long)r * N + col;
        val += uns(resH[ri], resL[ri]);
      }
      if constexpr (EPI == 0 || EPI == 4) {
        outF[(long)r * N + col] = val;
      } else if constexpr (EPI == 1) {
        long hi = (long)((r >> 10) * 1026 + (r & 1023) + 1) * 256 + col;
        unsigned short hs, ls;
        split2(val, hs, ls);
        outH[hi] = hs;
        outL[hi] = ls;
      } else if constexpr (EPI == 2) {
        int b_ = r >> 10, l = r & 1023, hq = col >> 6;
        long oidx = (((long)(b_ * 4 + hq) * 1024 + l) << 6) + (col & 63);
        outF[oidx] = val;
      } else if constexpr (EPI == 3) {
        long oi = (long)r * N + col;
        unsigned short hs, ls;
        split2(val, hs, ls);
        outH[oi] = hs;
        outL[oi] = ls;
      }
      if constexpr (ACC == 1) {
        acc4[(long)r * 256 + col] = val;
      } else if constexpr (ACC == 2) {
        acc4[(long)r * 256 + col] += val;
      }
    }
  }
}

// LayerNorm(256) -> hi/lo planes. 256 threads = 4 rows.
__global__ __launch_bounds__(256) void ln_pl(const float* __restrict__ in,
                                             unsigned short* __restrict__ oH,
                                             unsigned short* __restrict__ oL,
                                             const float* __restrict__ w,
                                             const float* __restrict__ bb,
                                             float eps) {
  int row = blockIdx.x * 4 + (threadIdx.x >> 6);
  int l = threadIdx.x & 63;
  float4 v = ((const float4*)(in + (long)row * 256))[l];
  float s = wsum(v.x + v.y + v.z + v.w);
  float mu = s * (1.0f / 256.0f);
  float dx = v.x - mu, dy = v.y - mu, dz = v.z - mu, dw = v.w - mu;
  float rstd = rsqrtf(wsum(dx * dx + dy * dy + dz * dz + dw * dw) * (1.0f / 256.0f) + eps);
  float4 wv = ((const float4*)w)[l];
  float4 bv = ((const float4*)bb)[l];
  float rr[4];
  rr[0] = wv.x * dx * rstd + bv.x;
  rr[1] = wv.y * dy * rstd + bv.y;
  rr[2] = wv.z * dz * rstd + bv.z;
  rr[3] = wv.w * dw * rstd + bv.w;
  long base = (long)row * 256 + l * 4;
#pragma unroll
  for (int j = 0; j < 4; ++j) {
    unsigned short hs, ls;
    split2(rr[j], hs, ls);
    oH[base + j] = hs;
    oL[base + j] = ls;
  }
}

// ---------------------------------------------------------------------------
// TTT scan via MFMA (R7 structure, verified): 512 threads (8 waves, 2/SIMD).
// Output written as hi/lo planes for the wo MFMA GEMM.
// ---------------------------------------------------------------------------
__global__ __launch_bounds__(512, 2) void ttt_mfma(
    const float* __restrict__ XQ, const float* __restrict__ XK,
    const float* __restrict__ XV, const float* __restrict__ W1i,
    const float* __restrict__ B1i, const float* __restrict__ W2i,
    const float* __restrict__ B2i, const float* __restrict__ LNW,
    const float* __restrict__ LNB, unsigned short* __restrict__ outH,
    unsigned short* __restrict__ outL) {
  extern __shared__ char smem[];
  unsigned short* W2Hp  = (unsigned short*)smem;   // [256][72]
  unsigned short* W2Lp  = W2Hp + 256 * 72;
  unsigned short* W2THp = W2Lp + 256 * 72;         // [64][264]
  unsigned short* W2TLp = W2THp + 64 * 264;
  unsigned short* X2Hp  = W2TLp + 64 * 264;        // [4][272]
  unsigned short* X2Lp  = X2Hp + 4 * 272;
  unsigned short* xkHp  = X2Lp + 4 * 272;          // [4][80]
  unsigned short* xkLp  = xkHp + 4 * 80;
  unsigned short* xqHp  = xkLp + 4 * 80;
  unsigned short* xqLp  = xqHp + 4 * 80;
  unsigned short* gZHp  = xqLp + 4 * 80;           // [4][80]
  unsigned short* gZLp  = gZHp + 4 * 80;
  float* X2F  = (float*)(gZLp + 4 * 80);           // [4][264] fp32 X2
  float* gZ1f = X2F + 4 * 264;                     // [4][256]
  float* Z2f  = gZ1f + 1024;                       // [4][64] gZ2 fp32
  float* redS = Z2f + 256;                         // [2][4][64]
  float* xvL  = redS + 512;                        // [4][64]
  float* b2L  = xvL + 256;                         // [64]
  float* lwL  = b2L + 64;
  float* lbL  = lwL + 64;

  const int bh = blockIdx.x, b = bh >> 2, h = bh & 3;
  const int t = threadIdx.x;           // 0..511
  const int w8 = t >> 6;
  const int lane = t & 63;
  const int a = lane & 15, g = lane >> 4;
  const bool rowv = (a < 4), g0 = (g == 0);
  const int c0 = 32 * w8 + a;
  const int c1 = 32 * w8 + 16 + a;
  const int kh = w8 & 1;
  const int jc = (w8 >> 1) * 16 + a;

  FB zf; zf.d[0] = zf.d[1] = zf.d[2] = zf.d[3] = 0;

  FB w1h[2][2], w1l[2][2];
#pragma unroll
  for (int i = 0; i < 2; ++i) {
    int cc = 32 * w8 + i * 16 + a;
#pragma unroll
    for (int kc = 0; kc < 2; ++kc) {
#pragma unroll
      for (int e = 0; e < 8; ++e) {
        int k = kc * 32 + g * 8 + e;
        unsigned p = pack_split(W1i[(h * 64 + k) * 256 + cc]);
        w1h[i][kc].u[e] = (unsigned short)(p >> 16);
        w1l[i][kc].u[e] = (unsigned short)(p & 0xFFFFu);
      }
    }
  }
  float b1r0 = B1i[h * 256 + c0];
  float b1r1 = B1i[h * 256 + c1];

  for (int i = 0; i < 32; ++i) {
    int id = t + i * 512;
    int k = id >> 6, j = id & 63;
    unsigned p = pack_split(W2i[(h * 256 + k) * 64 + j]);
    W2Hp[k * 72 + j] = (unsigned short)(p >> 16);
    W2Lp[k * 72 + j] = (unsigned short)(p & 0xFFFFu);
    int j2 = id >> 8, k2 = id & 255;
    unsigned q = pack_split(W2i[(h * 256 + k2) * 64 + j2]);
    W2THp[j2 * 264 + k2] = (unsigned short)(q >> 16);
    W2TLp[j2 * 264 + k2] = (unsigned short)(q & 0xFFFFu);
  }
  if (t < 64) { b2L[t] = B2i[h * 64 + t]; lwL[t] = LNW[h * 64 + t]; lbL[t] = LNB[h * 64 + t]; }

  const long chain = (long)bh * 65536;
  float rk = 0.f, rv = 0.f, rq = 0.f;
  if (t >= 256) {
    int u = t - 256;
    rk = XK[chain + u]; rv = XV[chain + u]; rq = XQ[chain + u];
  }

  for (int n = 0; n < 256; ++n) {
    if (t >= 256) {
      int u = t - 256, m = u >> 6, k = u & 63;
      unsigned short hs, ls;
      split2(rk, hs, ls); xkHp[m * 80 + k] = hs; xkLp[m * 80 + k] = ls;
      split2(rq, hs, ls); xqHp[m * 80 + k] = hs; xqLp[m * 80 + k] = ls;
      xvL[u] = rv;
    }
    __syncthreads();  // B1

    float gpA[4] = {0.f, 0.f, 0.f, 0.f}, gpB[4] = {0.f, 0.f, 0.f, 0.f};

    // ---- S1: Z1 = xk @ W1 + b1 ; in-reg gelu -> X2 planes + X2F ----
    {
      f32x4 A0 = (f32x4){b1r0, b1r0, b1r0, b1r0};
      f32x4 A1 = (f32x4){b1r1, b1r1, b1r1, b1r1};
#pragma unroll
      for (int kc = 0; kc < 2; ++kc) {
        int base = kc * 32 + g * 8;
        FB ah = zf, al = zf;
        if (rowv) {
          ah.v = *(const bfrag*)&xkHp[a * 80 + base];
          al.v = *(const bfrag*)&xkLp[a * 80 + base];
        }
        A0 = mm3(ah.v, al.v, w1h[0][kc].v, w1l[0][kc].v, A0);
        A1 = mm3(ah.v, al.v, w1h[1][kc].v, w1l[1][kc].v, A1);
      }
      if (g0) {
#pragma unroll
        for (int q = 0; q < 4; ++q) {
          float z = A0[q];
          float er = erff(z * ERF_CF);
          float hh = 0.5f * (1.0f + er);
          float x2 = z * hh;
          gpA[q] = hh + z * __expf(-0.5f * z * z) * PDF_CF;
          unsigned short hs, ls;
          split2(x2, hs, ls);
          X2Hp[q * 272 + c0] = hs; X2Lp[q * 272 + c0] = ls;
          X2F[q * 264 + c0] = x2;
          z = A1[q];
          er = erff(z * ERF_CF);
          hh = 0.5f * (1.0f + er);
          x2 = z * hh;
          gpB[q] = hh + z * __expf(-0.5f * z * z) * PDF_CF;
          split2(x2, hs, ls);
          X2Hp[q * 272 + c1] = hs; X2Lp[q * 272 + c1] = ls;
          X2F[q * 264 + c1] = x2;
        }
      }
    }
    __syncthreads();  // B2

    // ---- S2: Z2 partials (split-K over kh) ----
    {
      f32x4 acc = (f32x4){0.f, 0.f, 0.f, 0.f};
#pragma unroll
      for (int k4 = 0; k4 < 4; ++k4) {
        int base = (kh * 4 + k4) * 32 + g * 8;
        FB ah = zf, al = zf, bhf, blf;
        if (rowv) {
          ah.v = *(const bfrag*)&X2Hp[a * 272 + base];
          al.v = *(const bfrag*)&X2Lp[a * 272 + base];
        }
        bhf.v = *(const bfrag*)&W2THp[jc * 264 + base];
        blf.v = *(const bfrag*)&W2TLp[jc * 264 + base];
        acc = mm3(ah.v, al.v, bhf.v, blf.v, acc);
      }
      if (g0) {
#pragma unroll
        for (int q = 0; q < 4; ++q) redS[(kh * 4 + q) * 64 + jc] = acc[q];
      }
    }
    __syncthreads();  // B3

    // ---- LN-l2-bwd (waves 0-3) + prefetch (waves 4-7) ----
    if (t < 256) {
      int m = w8, j = lane;
      float z2 = b2L[j] + redS[m * 64 + j] + redS[256 + m * 64 + j];
      float mu = wsum(z2) * (1.0f / 64.0f);
      float dv = z2 - mu;
      float var = wsum(dv * dv) * (1.0f / 64.0f);
      float stdv = sqrtf(var + 1e-6f);
      float zh = dv / stdv;
      float lw = lwL[j], lb = lbL[j];
      float xkf = uns(xkHp[m * 80 + j], xkLp[m * 80 + j]);
      float tgt = xvL[m * 64 + j] - xkf;
      float gg = lw * (lw * zh + lb - tgt);
      float gs = wsum(gg) * (1.0f / 64.0f);
      float gzs = wsum(gg * zh) * (1.0f / 64.0f);
      float gz2 = (gg - gs - zh * gzs) / stdv;
      unsigned short hs, ls;
      split2(gz2, hs, ls);
      gZHp[m * 80 + j] = hs; gZLp[m * 80 + j] = ls;
      Z2f[m * 64 + j] = gz2;
    } else if (n + 1 < 256) {
      int u = t - 256;
      long nb = chain + (long)(n + 1) * 256;
      rk = XK[nb + u]; rv = XV[nb + u]; rq = XQ[nb + u];
    }
    __syncthreads();  // B4

    // ---- S3 (gZ1) overlapped with W2T RMW ----
    {
      f32x4 A0 = (f32x4){0.f, 0.f, 0.f, 0.f};
      f32x4 A1 = (f32x4){0.f, 0.f, 0.f, 0.f};
#pragma unroll
      for (int kc = 0; kc < 2; ++kc) {
        int base = kc * 32 + g * 8;
        FB ah = zf, al = zf, b0h, b0l, b1h, b1l;
        if (rowv) {
          ah.v = *(const bfrag*)&gZHp[a * 80 + base];
          al.v = *(const bfrag*)&gZLp[a * 80 + base];
        }
        b0h.v = *(const bfrag*)&W2Hp[c0 * 72 + base];
        b0l.v = *(const bfrag*)&W2Lp[c0 * 72 + base];
        b1h.v = *(const bfrag*)&W2Hp[c1 * 72 + base];
        b1l.v = *(const bfrag*)&W2Lp[c1 * 72 + base];
        A0 = mm3(ah.v, al.v, b0h.v, b0l.v, A0);
        A1 = mm3(ah.v, al.v, b1h.v, b1l.v, A1);
      }
      if (g0) {
#pragma unroll
        for (int q = 0; q < 4; ++q) {
          gZ1f[q * 256 + c0] = A0[q] * gpA[q];
          gZ1f[q * 256 + c1] = A1[q] * gpB[q];
        }
      }
      {
        int jr = t & 63, kb = (t >> 6) * 32;
        float gz0 = Z2f[jr], gz1 = Z2f[64 + jr], gz2 = Z2f[128 + jr], gz3 = Z2f[192 + jr];
#pragma unroll
        for (int kk = 0; kk < 32; kk += 8) {
          int kb8 = kb + kk;
          float x0[8], x1[8], x2[8], x3[8];
          *(float4*)&x0[0] = *(const float4*)&X2F[kb8];        *(float4*)&x0[4] = *(const float4*)&X2F[kb8 + 4];
          *(float4*)&x1[0] = *(const float4*)&X2F[264 + kb8];  *(float4*)&x1[4] = *(const float4*)&X2F[264 + kb8 + 4];
          *(float4*)&x2[0] = *(const float4*)&X2F[528 + kb8];  *(float4*)&x2[4] = *(const float4*)&X2F[528 + kb8 + 4];
          *(float4*)&x3[0] = *(const float4*)&X2F[792 + kb8];  *(float4*)&x3[4] = *(const float4*)&X2F[792 + kb8 + 4];
          FB oh, ol, nh, nl;
          oh.v = *(const bfrag*)&W2THp[jr * 264 + kb8];
          ol.v = *(const bfrag*)&W2TLp[jr * 264 + kb8];
#pragma unroll
          for (int e = 0; e < 8; ++e) {
            float uu = fmaf(x3[e], gz3, fmaf(x2[e], gz2, fmaf(x1[e], gz1, x0[e] * gz0)));
            float f = fmaf(-ETA, uu, fb_el(oh, ol, e));
            unsigned short hs, ls;
            split2(f, hs, ls);
            nh.u[e] = hs; nl.u[e] = ls;
          }
          *(bfrag*)&W2THp[jr * 264 + kb8] = nh.v;
          *(bfrag*)&W2TLp[jr * 264 + kb8] = nl.v;
        }
      }
    }
    __syncthreads();  // B5

    // ---- W1/b1 reg update ; S6 ; gelu ; W2 RMW ; b2 ----
    {
      float gzA0 = gZ1f[c0], gzA1 = gZ1f[256 + c0], gzA2 = gZ1f[512 + c0], gzA3 = gZ1f[768 + c0];
      float gzB0 = gZ1f[c1], gzB1 = gZ1f[256 + c1], gzB2 = gZ1f[512 + c1], gzB3 = gZ1f[768 + c1];
      b1r0 = fmaf(-ETA, ((gzA0 + gzA1) + gzA2) + gzA3, b1r0);
      b1r1 = fmaf(-ETA, ((gzB0 + gzB1) + gzB2) + gzB3, b1r1);
#pragma unroll
      for (int kc = 0; kc < 2; ++kc) {
        int base = kc * 32 + g * 8;
        FB x0h, x0l, x1h, x1l, x2h, x2l, x3h, x3l;
        x0h.v = *(const bfrag*)&xkHp[base];       x0l.v = *(const bfrag*)&xkLp[base];
        x1h.v = *(const bfrag*)&xkHp[80 + base];  x1l.v = *(const bfrag*)&xkLp[80 + base];
        x2h.v = *(const bfrag*)&xkHp[160 + base]; x2l.v = *(const bfrag*)&xkLp[160 + base];
        x3h.v = *(const bfrag*)&xkHp[240 + base]; x3l.v = *(const bfrag*)&xkLp[240 + base];
#pragma unroll
        for (int e = 0; e < 8; ++e) {
          float k0 = fb_el(x0h, x0l, e), k1 = fb_el(x1h, x1l, e);
          float k2 = fb_el(x2h, x2l, e), k3 = fb_el(x3h, x3l, e);
          float uA = fmaf(k3, gzA3, fmaf(k2, gzA2, fmaf(k1, gzA1, k0 * gzA0)));
          float uB = fmaf(k3, gzB3, fmaf(k2, gzB2, fmaf(k1, gzB1, k0 * gzB0)));
          float fA = fmaf(-ETA, uA, fb_el(w1h[0][kc], w1l[0][kc], e));
          float fB = fmaf(-ETA, uB, fb_el(w1h[1][kc], w1l[1][kc], e));
          unsigned short hs, ls;
          split2(fA, hs, ls); w1h[0][kc].u[e] = hs; w1l[0][kc].u[e] = ls;
          split2(fB, hs, ls); w1h[1][kc].u[e] = hs; w1l[1][kc].u[e] = ls;
        }
      }
      {
        f32x4 A0 = (f32x4){b1r0, b1r0, b1r0, b1r0};
        f32x4 A1 = (f32x4){b1r1, b1r1, b1r1, b1r1};
#pragma unroll
        for (int kc = 0; kc < 2; ++kc) {
          int base = kc * 32 + g * 8;
          FB ah = zf, al = zf;
          if (rowv) {
            ah.v = *(const bfrag*)&xqHp[a * 80 + base];
            al.v = *(const bfrag*)&xqLp[a * 80 + base];
          }
          A0 = mm3(ah.v, al.v, w1h[0][kc].v, w1l[0][kc].v, A0);
          A1 = mm3(ah.v, al.v, w1h[1][kc].v, w1l[1][kc].v, A1);
        }
        if (g0) {
#pragma unroll
          for (int q = 0; q < 4; ++q) {
            float z = A0[q];
            float x2 = 0.5f * z * (1.0f + erff(z * ERF_CF));
            unsigned short hs, ls;
            split2(x2, hs, ls);
            X2Hp[q * 272 + c0] = hs; X2Lp[q * 272 + c0] = ls;
            z = A1[q];
            x2 = 0.5f * z * (1.0f + erff(z * ERF_CF));
            split2(x2, hs, ls);
            X2Hp[q * 272 + c1] = hs; X2Lp[q * 272 + c1] = ls;
          }
        }
      }
      {
        int kr = t & 255, jh = (t >> 8) * 32;
        float xk0 = X2F[kr], xk1 = X2F[264 + kr], xk2 = X2F[528 + kr], xk3 = X2F[792 + kr];
#pragma unroll
        for (int jj = 0; jj < 32; jj += 8) {
          int jb = jh + jj;
          float g0f[8], g1f[8], g2f[8], g3f[8];
          *(float4*)&g0f[0] = *(const float4*)&Z2f[jb];        *(float4*)&g0f[4] = *(const float4*)&Z2f[jb + 4];
          *(float4*)&g1f[0] = *(const float4*)&Z2f[64 + jb];   *(float4*)&g1f[4] = *(const float4*)&Z2f[64 + jb + 4];
          *(float4*)&g2f[0] = *(const float4*)&Z2f[128 + jb];  *(float4*)&g2f[4] = *(const float4*)&Z2f[128 + jb + 4];
          *(float4*)&g3f[0] = *(const float4*)&Z2f[192 + jb];  *(float4*)&g3f[4] = *(const float4*)&Z2f[192 + jb + 4];
          FB oh, ol, nh, nl;
          oh.v = *(const bfrag*)&W2Hp[kr * 72 + jb];
          ol.v = *(const bfrag*)&W2Lp[kr * 72 + jb];
#pragma unroll
          for (int e = 0; e < 8; ++e) {
            float uu = fmaf(xk3, g3f[e], fmaf(xk2, g2f[e], fmaf(xk1, g1f[e], xk0 * g0f[e])));
            float f = fmaf(-ETA, uu, fb_el(oh, ol, e));
            unsigned short hs, ls;
            split2(f, hs, ls);
            nh.u[e] = hs; nl.u[e] = ls;
          }
          *(bfrag*)&W2Hp[kr * 72 + jb] = nh.v;
          *(bfrag*)&W2Lp[kr * 72 + jb] = nl.v;
        }
      }
      if (t < 64)
        b2L[t] -= ETA * (((Z2f[t] + Z2f[64 + t]) + Z2f[128 + t]) + Z2f[192 + t]);
    }
    __syncthreads();  // B6

    // ---- S7: Z2q partials (updated W2T) ----
    {
      f32x4 acc = (f32x4){0.f, 0.f, 0.f, 0.f};
#pragma unroll
      for (int k4 = 0; k4 < 4; ++k4) {
        int base = (kh * 4 + k4) * 32 + g * 8;
        FB ah = zf, al = zf, bhf, blf;
        if (rowv) {
          ah.v = *(const bfrag*)&X2Hp[a * 272 + base];
          al.v = *(const bfrag*)&X2Lp[a * 272 + base];
        }
        bhf.v = *(const bfrag*)&W2THp[jc * 264 + base];
        blf.v = *(const bfrag*)&W2TLp[jc * 264 + base];
        acc = mm3(ah.v, al.v, bhf.v, blf.v, acc);
      }
      if (g0) {
#pragma unroll
        for (int q = 0; q < 4; ++q) redS[(kh * 4 + q) * 64 + jc] = acc[q];
      }
    }
    __syncthreads();  // B7

    // ---- LN fwd + residual + output planes (waves 0-3) ----
    if (t < 256) {
      int m = w8, j = lane;
      float z = b2L[j] + redS[m * 64 + j] + redS[256 + m * 64 + j];
      float mu = wsum(z) * (1.0f / 64.0f);
      float dv = z - mu;
      float var = wsum(dv * dv) * (1.0f / 64.0f);
      float rstd = rsqrtf(var + 1e-6f);
      float xqf = uns(xqHp[m * 80 + j], xqLp[m * 80 + j]);
      float val = lwL[j] * dv * rstd + lbL[j] + xqf;
      long oidx = ((long)(b * 1024 + n * 4 + m)) * 256 + h * 64 + j;
      unsigned short hs, ls;
      split2(val, hs, ls);
      outH[oidx] = hs;
      outL[oidx] = ls;
    }
    __syncthreads();  // B8
  }
}

// final (4096,64) @ (64,1) + b
__global__ __launch_bounds__(256) void fc3_kernel(const float* __restrict__ f2,
                                                  const float* __restrict__ w,
                                                  const float* __restrict__ bias,
                                                  float* __restrict__ o) {
  int m = blockIdx.x * 4 + (threadIdx.x >> 6);
  int lane = threadIdx.x & 63;
  float v = f2[m * 64 + lane] * w[lane];
  v = wsum(v);
  if (lane == 0) o[m] = v + bias[0];
}

// ---------------------------------------------------------------------------
extern "C" void kernel_launch(void* const* d_in, const int* in_sizes, int n_in,
                              void* d_out, int out_size, void* d_ws, size_t ws_size,
                              hipStream_t stream) {
  const float* x       = (const float*)d_in[0];
  const float* conv1_w = (const float*)d_in[1];
  const float* conv1_b = (const float*)d_in[2];
  const float* convs_w = (const float*)d_in[3];
  const float* convs_b = (const float*)d_in[4];
  const float* ln_w    = (const float*)d_in[5];
  const float* ln_b    = (const float*)d_in[6];
  const float* wq      = (const float*)d_in[7];
  const float* wk      = (const float*)d_in[8];
  const float* wv      = (const float*)d_in[9];
  const float* wo      = (const float*)d_in[10];
  const float* ttt_W1  = (const float*)d_in[11];
  const float* ttt_b1  = (const float*)d_in[12];
  const float* ttt_W2  = (const float*)d_in[13];
  const float* ttt_b2  = (const float*)d_in[14];
  const float* ttt_lnw = (const float*)d_in[15];
  const float* ttt_lnb = (const float*)d_in[16];
  const float* fc_w    = (const float*)d_in[17];
  const float* fc_b    = (const float*)d_in[18];
  const float* fc2_w   = (const float*)d_in[19];
  const float* fc2_b   = (const float*)d_in[20];
  const float* fc3_w   = (const float*)d_in[21];
  const float* fc3_b   = (const float*)d_in[22];

  // ---- workspace layout (ushort units), total 37.4MB < proven 39.9MB ----
  unsigned short* U = (unsigned short*)d_ws;
  unsigned short* WH   = U;                 // 2,015,232 (all weight hi planes)
  unsigned short* WL   = U + 2015232;       // lo planes
  unsigned short* cAH  = U + 4030464;       // conv halo planes A (1,050,624)
  unsigned short* cAL  = U + 5081088;
  unsigned short* cBH  = U + 6131712;
  unsigned short* cBL  = U + 7182336;
  unsigned short* tlnH = U + 8232960;       // 1,048,576
  unsigned short* tlnL = U + 9281536;
  unsigned short* toH  = U + 10330112;
  unsigned short* toL  = U + 11378688;
  float* F = (float*)d_ws;
  float* sum4 = F + 6213632;                // == XQ == tfull (time-aliased)
  float* XQ   = sum4;
  float* tfull = sum4;
  float* XK   = F + 7262208;
  float* XV   = F + 8310784;
  unsigned short* f1H = (unsigned short*)XK;   // f1 planes over dead XK/XV
  unsigned short* f1L = (unsigned short*)XV;
  float* f2 = (float*)toH;                     // over dead tout planes
  unsigned short* h2H = cAH;                   // over dead conv planes
  unsigned short* h2L = cAL;

  // weight plane offsets inside WH/WL
  const int W_WT1 = 0, W_WT = 16384, W_QKVO = 1589248, W_FC = 1851392, W_FC2 = 1982464;

  dim3 blk(256);

  zero_halo_pl<<<32, blk, 0, stream>>>(cAH, cAL, cBH, cBL);
  prep_all<<<7872, blk, 0, stream>>>(conv1_w, convs_w, wq, wk, wv, wo, fc_w,
                                     fc2_w, WH, WL);

  // conv1 (1x1, A=x fp32) -> halo planes A
  gemm_mf<1, 0, 1, 1, 1, 0><<<dim3(128, 4), blk, 0, stream>>>(
      nullptr, nullptr, x, WH + W_WT1, WL + W_WT1, conv1_b, nullptr, nullptr,
      nullptr, cAH, cAL, nullptr, 256, 64);

  // 8 sequential convs; acts 1,3,5,7 accumulate into sum4
  for (int i = 0; i < 8; ++i) {
    const unsigned short* iH = (i % 2 == 0) ? cAH : cBH;
    const unsigned short* iL = (i % 2 == 0) ? cAL : cBL;
    unsigned short* oH = (i % 2 == 0) ? cBH : cAH;
    unsigned short* oL = (i % 2 == 0) ? cBL : cAL;
    const unsigned short* bH = WH + W_WT + i * 196608;
    const unsigned short* bL = WL + W_WT + i * 196608;
    const float* bp = convs_b + i * 256;
    if (i == 1)
      gemm_mf<0, 1, 1, 1, 1, 1><<<dim3(128, 4), blk, 0, stream>>>(
          iH, iL, nullptr, bH, bL, bp, nullptr, nullptr, nullptr, oH, oL, sum4,
          256, 768);
    else if (i == 3 || i == 5 || i == 7)
      gemm_mf<0, 1, 1, 1, 1, 2><<<dim3(128, 4), blk, 0, stream>>>(
          iH, iL, nullptr, bH, bL, bp, nullptr, nullptr, nullptr, oH, oL, sum4,
          256, 768);
    else
      gemm_mf<0, 1, 1, 1, 1, 0><<<dim3(128, 4), blk, 0, stream>>>(
          iH, iL, nullptr, bH, bL, bp, nullptr, nullptr, nullptr, oH, oL,
          nullptr, 256, 768);
  }

  // LN #1: sum4 -> tln planes
  ln_pl<<<1024, blk, 0, stream>>>(sum4, tlnH, tlnL, ln_w, ln_b, 1e-5f);

  // QKV projections (scatter to (B,H,L,64) fp32)
  gemm_mf<0, 0, 0, 0, 2, 0><<<dim3(128, 4), blk, 0, stream>>>(
      tlnH, tlnL, nullptr, WH + W_QKVO + 0 * 65536, WL + W_QKVO + 0 * 65536,
      nullptr, nullptr, nullptr, XQ, nullptr, nullptr, nullptr, 256, 256);
  gemm_mf<0, 0, 0, 0, 2, 0><<<dim3(128, 4), blk, 0, stream>>>(
      tlnH, tlnL, nullptr, WH + W_QKVO + 1 * 65536, WL + W_QKVO + 1 * 65536,
      nullptr, nullptr, nullptr, XK, nullptr, nullptr, nullptr, 256, 256);
  gemm_mf<0, 0, 0, 0, 2, 0><<<dim3(128, 4), blk, 0, stream>>>(
      tlnH, tlnL, nullptr, WH + W_QKVO + 2 * 65536, WL + W_QKVO + 2 * 65536,
      nullptr, nullptr, nullptr, XV, nullptr, nullptr, nullptr, 256, 256);

  // TTT scan (R7 kernel): 16 chains, 512 threads, 162688 B dynamic LDS
  const int TTT_LDS = 162688;
  (void)hipFuncSetAttribute((const void*)ttt_mfma,
                            hipFuncAttributeMaxDynamicSharedMemorySize, TTT_LDS);
  ttt_mfma<<<16, dim3(512), TTT_LDS, stream>>>(XQ, XK, XV, ttt_W1, ttt_b1,
                                               ttt_W2, ttt_b2, ttt_lnw, ttt_lnb,
                                               toH, toL);

  // tfull = tout @ wo + tln   (residual from tln planes; fp32 out over dead XQ)
  gemm_mf<0, 0, 0, 0, 4, 0><<<dim3(128, 4), blk, 0, stream>>>(
      toH, toL, nullptr, WH + W_QKVO + 3 * 65536, WL + W_QKVO + 3 * 65536,
      nullptr, tlnH, tlnL, tfull, nullptr, nullptr, nullptr, 256, 256);

  // LN #2: tfull -> h2 planes
  ln_pl<<<1024, blk, 0, stream>>>(tfull, h2H, h2L, ln_w, ln_b, 1e-5f);

  // fc (256->512) -> f1 planes; fc2 (512->64) -> f2 fp32; fc3 -> out
  gemm_mf<0, 0, 1, 0, 3, 0><<<dim3(128, 8), blk, 0, stream>>>(
      h2H, h2L, nullptr, WH + W_FC, WL + W_FC, fc_b, nullptr, nullptr, nullptr,
      f1H, f1L, nullptr, 512, 256);
  gemm_mf<0, 0, 1, 0, 0, 0><<<dim3(128, 1), blk, 0, stream>>>(
      f1H, f1L, nullptr, WH + W_FC2, WL + W_FC2, fc2_b, nullptr, nullptr, f2,
      nullptr, nullptr, nullptr, 64, 512);
  fc3_kernel<<<1024, blk, 0, stream>>>(f2, fc3_w, fc3_b, (float*)d_out);
}